// Round 21
// baseline (109.928 us; speedup 1.0000x reference)
//
#include <hip/hip_runtime.h>
#include <math.h>

#define N1 8192
#define N2 8192
#define KS 4096   // K-range per gemm block (2-way K-split)
#define PLANE (8192 * 256)   // elements per [row][kc] partial plane
// 40.5 * log2(e) and 2x that: exp(-40.5*d2) = exp2(-B2L*d2)
#define B2L  58.42914916f
#define B2L2 116.85829832f

typedef short bf16x8 __attribute__((ext_vector_type(8)));
typedef float f32x4 __attribute__((ext_vector_type(4)));
typedef unsigned short ushort8 __attribute__((ext_vector_type(8)));

// Light barrier: LDS-only coherence; in-flight global loads stay in flight.
#define LBAR() do { \
    asm volatile("s_waitcnt lgkmcnt(0)" ::: "memory"); \
    __builtin_amdgcn_s_barrier(); \
} while (0)

__device__ __forceinline__ unsigned short bf16bits(float f) {
    union { float f; unsigned u; } x; x.f = f;
    unsigned r = x.u + 0x7fff + ((x.u >> 16) & 1);   // RNE
    return (unsigned short)(r >> 16);
}

__device__ __forceinline__ float bf2f(unsigned short b) {
    union { unsigned u; float f; } x; x.u = (unsigned)b << 16;
    return x.f;
}

// one v_cvt_pk_bf16_f32: D[15:0]=bf16(a), D[31:16]=bf16(b)
__device__ __forceinline__ unsigned int cvt_pk_bf16(float a, float b) {
    unsigned int r;
    asm("v_cvt_pk_bf16_f32 %0, %1, %2" : "=v"(r) : "v"(a), "v"(b));
    return r;
}

// raw v_exp_f32 (2^x), no OCML guard code.
__device__ __forceinline__ float fast_exp2(float x) {
    float r;
    asm("v_exp_f32 %0, %1" : "=v"(r) : "v"(x));
    return r;
}

// Native v_sin/v_cos: input in REVOLUTIONS, reduce with fract first.
__device__ __forceinline__ void fast_sincos(float th, float& s, float& c) {
    float r = th * 0.15915494309189535f;   // 1/(2*pi)
    r = r - floorf(r);
    asm("v_sin_f32 %0, %1" : "=v"(s) : "v"(r));
    asm("v_cos_f32 %0, %1" : "=v"(c) : "v"(r));
}

// Vf layout: [kblock = k/8][n = 0..511][e = k%8] bf16.
__global__ __launch_bounds__(512) void feat_kernel(const float* __restrict__ p2,
                                                   const float* __restrict__ A,
                                                   unsigned short* __restrict__ Vf) {
    __shared__ float p2s[24];
    const int t = threadIdx.x;
    const int j0 = blockIdx.x * 8;
    if (t < 24) p2s[t] = p2[(size_t)j0 * 3 + t];
    __syncthreads();
    const int k = t & 255, part = t >> 8;
    const float a0 = A[k], a1 = A[256 + k], a2 = A[512 + k];
    ushort8 v8;
    #pragma unroll
    for (int j = 0; j < 8; ++j) {
        float th = fmaf(p2s[j * 3], a0, fmaf(p2s[j * 3 + 1], a1, p2s[j * 3 + 2] * a2));
        float s, c;
        fast_sincos(th, s, c);
        v8[j] = bf16bits(part ? s : c);
    }
    *(ushort8*)(Vf + (size_t)blockIdx.x * 4096 + t * 8) = v8;
}

// qoff = kp*6 (thread-const); kbase*3 is uniform -> SALU base.
__device__ __forceinline__ void loadQ(const float* __restrict__ p2, int kbase, int qoff,
                                      float& qx0, float& qy0, float& qz0, float& e20,
                                      float& qx1, float& qy1, float& qz1, float& e21) {
    const float* q = p2 + (size_t)(unsigned)(kbase * 3) + qoff;
    qx0 = q[0]; qy0 = q[1]; qz0 = q[2];
    qx1 = q[3]; qy1 = q[4]; qz1 = q[5];
    e20 = -B2L * fmaf(qx0, qx0, fmaf(qy0, qy0, qz0 * qz0));
    e21 = -B2L * fmaf(qx1, qx1, fmaf(qy1, qy1, qz1 * qz1));
}

// J 64x64 subtile build (byte-identical mapping to R20): thread owns k-pair
// kp (0..31) x rows tm + 16*rr (rr<4): 8 exp per subtile.
__device__ __forceinline__ void buildJ(unsigned int* __restrict__ Jdst, const int wrOfs[4],
                                       const float px[4], const float py[4],
                                       const float pz[4], const float e1[4],
                                       float qx0, float qy0, float qz0, float e20,
                                       float qx1, float qy1, float qz1, float e21) {
    #pragma unroll
    for (int rr = 0; rr < 4; ++rr) {
        float s0 = fmaf(px[rr], qx0, fmaf(py[rr], qy0, pz[rr] * qz0));
        float s1 = fmaf(px[rr], qx1, fmaf(py[rr], qy1, pz[rr] * qz1));
        float j0 = fast_exp2(fmaf(s0, B2L2, e1[rr] + e20));
        float j1 = fast_exp2(fmaf(s1, B2L2, e1[rr] + e21));
        *(unsigned int*)((char*)Jdst + wrOfs[rr]) = cvt_pk_bf16(j0, j1);
    }
}

__device__ __forceinline__ void loadB(bf16x8 b[2][2], const unsigned short* __restrict__ pB,
                                      const int bOfs[2][2]) {
    #pragma unroll
    for (int kk = 0; kk < 2; ++kk)
        #pragma unroll
        for (int nr = 0; nr < 2; ++nr)
            b[kk][nr] = *(const bf16x8*)(pB + bOfs[kk][nr]);
}

__device__ __forceinline__ void mfmaStep(f32x4 acc[4][2], const unsigned int* __restrict__ Jsrc,
                                         bf16x8 b[2][2], const int rdOfs[2][4]) {
    #pragma unroll
    for (int kk = 0; kk < 2; ++kk)
        #pragma unroll
        for (int mr = 0; mr < 4; ++mr) {
            bf16x8 af = *(const bf16x8*)((const char*)Jsrc + rdOfs[kk][mr]);
            acc[mr][0] = __builtin_amdgcn_mfma_f32_16x16x32_bf16(af, b[kk][0], acc[mr][0], 0, 0, 0);
            acc[mr][1] = __builtin_amdgcn_mfma_f32_16x16x32_bf16(af, b[kk][1], acc[mr][1], 0, 0, 0);
        }
}

// BM=64 x BN=256 (cg) x K-half (ks). Grid 512, 512 threads, 2 blocks/CU.
// R20 base with BK=128 PHASES: JA/JB hold TWO 64x64 subtiles (+2048 uints);
// one barrier per 128 k (32/block, was 64). Each subtile's build/consume is
// byte-identical to R20 (R4's BK=128 failure rebuilt the mapping; this one
// does not). loadB/loadQ reloads are WAR-pinned after their consume and have
// a full buildJ (~200cyc) or phase of flight time.
__global__ __launch_bounds__(512, 4) void gemm_kernel(const float* __restrict__ p1,
                                                      const float* __restrict__ p2,
                                                      const unsigned short* __restrict__ Vf,
                                                      unsigned short* __restrict__ pout0,
                                                      unsigned short* __restrict__ pout1) {
    __shared__ unsigned int JA[4096];   // 2 subtiles x (64 rows x 64 k) bf16, XOR-swizzled
    __shared__ unsigned int JB[4096];

    const int t = threadIdx.x;
    const int l = t & 63;
    const int w = t >> 6;         // 0..7: col group (32 cols of the 256)
    const int g = l >> 4;
    const int ln = l & 15;
    const int bid = (int)blockIdx.x;
    const int cg = bid & 1;
    const int ks = (bid >> 1) & 1;
    const int i0 = (bid >> 2) * 64;
    const int k0 = ks * KS;

    // J-build: thread owns k-pair kp (0..31) x rows tm + 16*rr
    const int kp = t & 31;
    const int tm = t >> 5;        // 0..15
    const int qoff = kp * 6;
    float px[4], py[4], pz[4], e1[4];
    int wrOfs[4];
    #pragma unroll
    for (int rr = 0; rr < 4; ++rr) {
        const float* pp = p1 + (size_t)(i0 + tm + rr * 16) * 3;
        px[rr] = pp[0]; py[rr] = pp[1]; pz[rr] = pp[2];
        e1[rr] = -B2L * fmaf(px[rr], px[rr], fmaf(py[rr], py[rr], pz[rr] * pz[rr]));
        int m = tm + rr * 16;
        wrOfs[rr] = (m * 128 + kp * 4) ^ ((m & 7) << 4);
    }

    int rdOfs[2][4];
    #pragma unroll
    for (int kk = 0; kk < 2; ++kk)
        #pragma unroll
        for (int mr = 0; mr < 4; ++mr) {
            int m = mr * 16 + ln;
            rdOfs[kk][mr] = (m * 128 + kk * 64 + g * 16) ^ ((m & 7) << 4);
        }

    int bOfs[2][2];
    #pragma unroll
    for (int kk = 0; kk < 2; ++kk)
        #pragma unroll
        for (int nr = 0; nr < 2; ++nr)
            bOfs[kk][nr] = (kk * 4 + g) * 4096 + (cg * 256 + w * 32 + nr * 16 + ln) * 8;

    f32x4 acc[4][2] = {};

    bf16x8 bS[2][2];   // single B buffer, reloaded after each consume (WAR-pinned)
    float qx0, qy0, qz0, e20, qx1, qy1, qz1, e21;   // q set S0 (even 64-k subtiles)
    float rx0, ry0, rz0, f20, rx1, ry1, rz1, f21;   // q set S1 (odd 64-k subtiles)

    // prologue: JA <- [k0, k0+64), [k0+64, k0+128); q -> next phase; bS <- k0
    loadQ(p2, k0, qoff, qx0, qy0, qz0, e20, qx1, qy1, qz1, e21);
    buildJ(JA, wrOfs, px, py, pz, e1, qx0, qy0, qz0, e20, qx1, qy1, qz1, e21);
    loadQ(p2, k0 + 64, qoff, rx0, ry0, rz0, f20, rx1, ry1, rz1, f21);
    buildJ(JA + 2048, wrOfs, px, py, pz, e1, rx0, ry0, rz0, f20, rx1, ry1, rz1, f21);
    loadQ(p2, k0 + 128, qoff, qx0, qy0, qz0, e20, qx1, qy1, qz1, e21);
    loadQ(p2, k0 + 192, qoff, rx0, ry0, rz0, f20, rx1, ry1, rz1, f21);
    loadB(bS, Vf + ((unsigned)k0 >> 3) * 4096u, bOfs);

    for (int jc = k0; jc < k0 + KS; jc += 256) {
        // ---- phase 1: consume JA (k=jc..jc+127), build JB (jc+128..jc+255) ----
        LBAR();
        buildJ(JB, wrOfs, px, py, pz, e1, qx0, qy0, qz0, e20, qx1, qy1, qz1, e21);
        loadQ(p2, (jc + 256) & (N2 - 1), qoff, qx0, qy0, qz0, e20, qx1, qy1, qz1, e21);
        mfmaStep(acc, JA, bS, rdOfs);
        loadB(bS, Vf + ((unsigned)((jc + 64) & (N2 - 1)) >> 3) * 4096u, bOfs);
        buildJ(JB + 2048, wrOfs, px, py, pz, e1, rx0, ry0, rz0, f20, rx1, ry1, rz1, f21);
        loadQ(p2, (jc + 320) & (N2 - 1), qoff, rx0, ry0, rz0, f20, rx1, ry1, rz1, f21);
        mfmaStep(acc, JA + 2048, bS, rdOfs);
        loadB(bS, Vf + ((unsigned)((jc + 128) & (N2 - 1)) >> 3) * 4096u, bOfs);
        // ---- phase 2: consume JB (jc+128..jc+255), build JA (jc+256..jc+383) ----
        LBAR();
        buildJ(JA, wrOfs, px, py, pz, e1, qx0, qy0, qz0, e20, qx1, qy1, qz1, e21);
        loadQ(p2, (jc + 384) & (N2 - 1), qoff, qx0, qy0, qz0, e20, qx1, qy1, qz1, e21);
        mfmaStep(acc, JB, bS, rdOfs);
        loadB(bS, Vf + ((unsigned)((jc + 192) & (N2 - 1)) >> 3) * 4096u, bOfs);
        buildJ(JA + 2048, wrOfs, px, py, pz, e1, rx0, ry0, rz0, f20, rx1, ry1, rz1, f21);
        loadQ(p2, (jc + 448) & (N2 - 1), qoff, rx0, ry0, rz0, f20, rx1, ry1, rz1, f21);
        mfmaStep(acc, JB + 2048, bS, rdOfs);
        loadB(bS, Vf + ((unsigned)((jc + 256) & (N2 - 1)) >> 3) * 4096u, bOfs);
    }

    // ---- store raw partial C as bf16, planar [comp][row][kc] ----
    unsigned short* outb = (ks ? pout1 : pout0) + (size_t)cg * PLANE;
    #pragma unroll
    for (int mr = 0; mr < 4; ++mr) {
        #pragma unroll
        for (int reg = 0; reg < 4; ++reg) {
            int row = i0 + mr * 16 + g * 4 + reg;
            #pragma unroll
            for (int nr = 0; nr < 2; ++nr) {
                int kc = w * 32 + nr * 16 + ln;
                outb[(size_t)row * 256 + kc] = bf16bits(acc[mr][nr][reg]);
            }
        }
    }
}

// Epilogue: block per row. Sum the two bf16 K-half partials, reduce row norm,
// scale to 16, rotate by conj(exp(i p1.A)), add exp(i p1.P), write f32 out.
__global__ __launch_bounds__(256) void epi_kernel(const float* __restrict__ p1,
                                                  const float* __restrict__ A,
                                                  const float* __restrict__ P,
                                                  const unsigned short* __restrict__ part0,
                                                  const unsigned short* __restrict__ part1,
                                                  float* __restrict__ out) {
    __shared__ float wsum[4];
    const int i = blockIdx.x;
    const int k = threadIdx.x;
    const size_t rofs = (size_t)i * 256 + k;
    const float gr = bf2f(part0[rofs]) + bf2f(part1[rofs]);
    const float gi = bf2f(part0[PLANE + rofs]) + bf2f(part1[PLANE + rofs]);

    float sq = fmaf(gr, gr, gi * gi);
    #pragma unroll
    for (int off = 1; off < 64; off <<= 1) sq += __shfl_xor(sq, off, 64);
    if ((k & 63) == 0) wsum[k >> 6] = sq;
    __syncthreads();
    const float ns = wsum[0] + wsum[1] + wsum[2] + wsum[3];
    const float scale = 16.0f * rsqrtf(ns);

    const float x = p1[(size_t)i * 3 + 0], y = p1[(size_t)i * 3 + 1], z = p1[(size_t)i * 3 + 2];
    float th1 = fmaf(x, A[k], fmaf(y, A[256 + k], z * A[512 + k]));
    float thp = fmaf(x, P[k], fmaf(y, P[256 + k], z * P[512 + k]));
    float s1, c1, sp, cp;
    fast_sincos(th1, s1, c1);
    fast_sincos(thp, sp, cp);
    float2 res;
    res.x = fmaf(gr, c1, gi * s1) * scale + cp;
    res.y = fmaf(gi, c1, -gr * s1) * scale + sp;
    *(float2*)(out + rofs * 2) = res;
}

extern "C" void kernel_launch(void* const* d_in, const int* in_sizes, int n_in,
                              void* d_out, int out_size, void* d_ws, size_t ws_size,
                              hipStream_t stream) {
    const float* p1 = (const float*)d_in[0];
    const float* p2 = (const float*)d_in[1];
    const float* A  = (const float*)d_in[2];
    const float* P  = (const float*)d_in[3];
    unsigned short* Vf = (unsigned short*)d_ws;                            // 8.39 MB
    unsigned short* part0 = (unsigned short*)((char*)d_ws + 8388608);      // 8.39 MB bf16 [2][8192][256]
    unsigned short* part1 = (unsigned short*)((char*)d_ws + 16777216);     // 8.39 MB bf16
    float* out = (float*)d_out;

    feat_kernel<<<N2 / 8, 512, 0, stream>>>(p2, A, Vf);
    gemm_kernel<<<512, 512, 0, stream>>>(p1, p2, Vf, part0, part1);
    epi_kernel<<<N1, 256, 0, stream>>>(p1, A, P, part0, part1, out);
}

// Round 22
// 108.546 us; speedup vs baseline: 1.0127x; 1.0127x over previous
//
#include <hip/hip_runtime.h>
#include <math.h>

#define N1 8192
#define N2 8192
#define KS 4096   // K-range per gemm block (2-way K-split)
#define PLANE (8192 * 256)   // elements per [row][kc] partial plane
// 40.5 * log2(e) and 2x that: exp(-40.5*d2) = exp2(-B2L*d2)
#define B2L  58.42914916f
#define B2L2 116.85829832f

typedef short bf16x8 __attribute__((ext_vector_type(8)));
typedef float f32x4 __attribute__((ext_vector_type(4)));
typedef unsigned short ushort8 __attribute__((ext_vector_type(8)));

// Light barrier: LDS-only coherence; in-flight global loads stay in flight.
#define LBAR() do { \
    asm volatile("s_waitcnt lgkmcnt(0)" ::: "memory"); \
    __builtin_amdgcn_s_barrier(); \
} while (0)

__device__ __forceinline__ unsigned short bf16bits(float f) {
    union { float f; unsigned u; } x; x.f = f;
    unsigned r = x.u + 0x7fff + ((x.u >> 16) & 1);   // RNE
    return (unsigned short)(r >> 16);
}

__device__ __forceinline__ float bf2f(unsigned short b) {
    union { unsigned u; float f; } x; x.u = (unsigned)b << 16;
    return x.f;
}

// one v_cvt_pk_bf16_f32: D[15:0]=bf16(a), D[31:16]=bf16(b)
__device__ __forceinline__ unsigned int cvt_pk_bf16(float a, float b) {
    unsigned int r;
    asm("v_cvt_pk_bf16_f32 %0, %1, %2" : "=v"(r) : "v"(a), "v"(b));
    return r;
}

// raw v_exp_f32 (2^x), no OCML guard code. Args <= 0; sub-2^-126 results
// flush toward 0, which bf16 rounds to 0 anyway.
__device__ __forceinline__ float fast_exp2(float x) {
    float r;
    asm("v_exp_f32 %0, %1" : "=v"(r) : "v"(x));
    return r;
}

// Native v_sin/v_cos: input in REVOLUTIONS, reduce with fract first.
// ~6 inst vs ~40 for OCML sincosf. Validated R17-R20: absmax unchanged.
__device__ __forceinline__ void fast_sincos(float th, float& s, float& c) {
    float r = th * 0.15915494309189535f;   // 1/(2*pi)
    r = r - floorf(r);
    asm("v_sin_f32 %0, %1" : "=v"(s) : "v"(r));
    asm("v_cos_f32 %0, %1" : "=v"(c) : "v"(r));
}

// Vf layout: [kblock = k/8][n = 0..511][e = k%8] bf16.
// n in 0..255 -> cos(p2_k . A_n); n in 256..511 -> sin(p2_k . A_n).
__global__ __launch_bounds__(512) void feat_kernel(const float* __restrict__ p2,
                                                   const float* __restrict__ A,
                                                   unsigned short* __restrict__ Vf) {
    __shared__ float p2s[24];
    const int t = threadIdx.x;
    const int j0 = blockIdx.x * 8;
    if (t < 24) p2s[t] = p2[(size_t)j0 * 3 + t];
    __syncthreads();
    const int k = t & 255, part = t >> 8;
    const float a0 = A[k], a1 = A[256 + k], a2 = A[512 + k];
    ushort8 v8;
    #pragma unroll
    for (int j = 0; j < 8; ++j) {
        float th = fmaf(p2s[j * 3], a0, fmaf(p2s[j * 3 + 1], a1, p2s[j * 3 + 2] * a2));
        float s, c;
        fast_sincos(th, s, c);
        v8[j] = bf16bits(part ? s : c);
    }
    *(ushort8*)(Vf + (size_t)blockIdx.x * 4096 + t * 8) = v8;
}

// qoff = kp*6 (thread-const); kbase*3 is uniform -> SALU base.
__device__ __forceinline__ void loadQ(const float* __restrict__ p2, int kbase, int qoff,
                                      float& qx0, float& qy0, float& qz0, float& e20,
                                      float& qx1, float& qy1, float& qz1, float& e21) {
    const float* q = p2 + (size_t)(unsigned)(kbase * 3) + qoff;
    qx0 = q[0]; qy0 = q[1]; qz0 = q[2];
    qx1 = q[3]; qy1 = q[4]; qz1 = q[5];
    e20 = -B2L * fmaf(qx0, qx0, fmaf(qy0, qy0, qz0 * qz0));
    e21 = -B2L * fmaf(qx1, qx1, fmaf(qy1, qy1, qz1 * qz1));
}

// J tile build: 64 rows x 64 k, 512 threads -> thread owns k-pair kp (0..31)
// x rows tm + 16*rr (rr<4): 8 exp per step.
__device__ __forceinline__ void buildJ(unsigned int* __restrict__ Jdst, const int wrOfs[4],
                                       const float px[4], const float py[4],
                                       const float pz[4], const float e1[4],
                                       float qx0, float qy0, float qz0, float e20,
                                       float qx1, float qy1, float qz1, float e21) {
    #pragma unroll
    for (int rr = 0; rr < 4; ++rr) {
        float s0 = fmaf(px[rr], qx0, fmaf(py[rr], qy0, pz[rr] * qz0));
        float s1 = fmaf(px[rr], qx1, fmaf(py[rr], qy1, pz[rr] * qz1));
        float j0 = fast_exp2(fmaf(s0, B2L2, e1[rr] + e20));
        float j1 = fast_exp2(fmaf(s1, B2L2, e1[rr] + e21));
        *(unsigned int*)((char*)Jdst + wrOfs[rr]) = cvt_pk_bf16(j0, j1);
    }
}

__device__ __forceinline__ void loadB(bf16x8 b[2][2], const unsigned short* __restrict__ pB,
                                      const int bOfs[2][2]) {
    #pragma unroll
    for (int kk = 0; kk < 2; ++kk)
        #pragma unroll
        for (int nr = 0; nr < 2; ++nr)
            b[kk][nr] = *(const bf16x8*)(pB + bOfs[kk][nr]);
}

__device__ __forceinline__ void mfmaStep(f32x4 acc[4][2], const unsigned int* __restrict__ Jsrc,
                                         bf16x8 b[2][2], const int rdOfs[2][4]) {
    #pragma unroll
    for (int kk = 0; kk < 2; ++kk)
        #pragma unroll
        for (int mr = 0; mr < 4; ++mr) {
            bf16x8 af = *(const bf16x8*)((const char*)Jsrc + rdOfs[kk][mr]);
            acc[mr][0] = __builtin_amdgcn_mfma_f32_16x16x32_bf16(af, b[kk][0], acc[mr][0], 0, 0, 0);
            acc[mr][1] = __builtin_amdgcn_mfma_f32_16x16x32_bf16(af, b[kk][1], acc[mr][1], 0, 0, 0);
        }
}

// BM=64 x BN=256 (cg) x K-half (ks). Grid 512, 512 threads, 2 blocks/CU.
// Champion structure (R20, 108.8us total): single-buffer cross-barrier B
// prefetch (WAR-pinned loadB after its consume), lgkm-only barriers, bf16
// planar partials. ks/cg in bid bits 0-1 -> each XCD's B slice = 2.1MB,
// L2-resident. VGPR 60, no spill (WRITE must be 16384 KB).
// Further phase-restructuring is blocked by the 64-VGPR occupancy wall:
// (512,8)/1024-thr/dbuf-reg/BK=128 all spill or serialize (R7,R10-13,R15,R21).
__global__ __launch_bounds__(512, 4) void gemm_kernel(const float* __restrict__ p1,
                                                      const float* __restrict__ p2,
                                                      const unsigned short* __restrict__ Vf,
                                                      unsigned short* __restrict__ pout0,
                                                      unsigned short* __restrict__ pout1) {
    __shared__ unsigned int JA[2048];   // 64 rows x 64 k bf16, XOR-swizzled
    __shared__ unsigned int JB[2048];

    const int t = threadIdx.x;
    const int l = t & 63;
    const int w = t >> 6;         // 0..7: col group (32 cols of the 256)
    const int g = l >> 4;
    const int ln = l & 15;
    const int bid = (int)blockIdx.x;
    const int cg = bid & 1;
    const int ks = (bid >> 1) & 1;
    const int i0 = (bid >> 2) * 64;
    const int k0 = ks * KS;

    // J-build: thread owns k-pair kp (0..31) x rows tm + 16*rr
    const int kp = t & 31;
    const int tm = t >> 5;        // 0..15
    const int qoff = kp * 6;
    float px[4], py[4], pz[4], e1[4];
    int wrOfs[4];
    #pragma unroll
    for (int rr = 0; rr < 4; ++rr) {
        const float* pp = p1 + (size_t)(i0 + tm + rr * 16) * 3;
        px[rr] = pp[0]; py[rr] = pp[1]; pz[rr] = pp[2];
        e1[rr] = -B2L * fmaf(px[rr], px[rr], fmaf(py[rr], py[rr], pz[rr] * pz[rr]));
        int m = tm + rr * 16;
        wrOfs[rr] = (m * 128 + kp * 4) ^ ((m & 7) << 4);
    }

    int rdOfs[2][4];
    #pragma unroll
    for (int kk = 0; kk < 2; ++kk)
        #pragma unroll
        for (int mr = 0; mr < 4; ++mr) {
            int m = mr * 16 + ln;
            rdOfs[kk][mr] = (m * 128 + kk * 64 + g * 16) ^ ((m & 7) << 4);
        }

    int bOfs[2][2];
    #pragma unroll
    for (int kk = 0; kk < 2; ++kk)
        #pragma unroll
        for (int nr = 0; nr < 2; ++nr)
            bOfs[kk][nr] = (kk * 4 + g) * 4096 + (cg * 256 + w * 32 + nr * 16 + ln) * 8;

    f32x4 acc[4][2] = {};

    bf16x8 bS[2][2];   // single B buffer: reloaded after each consume (WAR-pinned)
    float qx0, qy0, qz0, e20, qx1, qy1, qz1, e21;   // q set "A-side"
    float rx0, ry0, rz0, f20, rx1, ry1, rz1, f21;   // q set "B-side"

    // prologue: J(k0) -> JA, B(k0) -> bS, q(k0+64) -> r
    loadQ(p2, k0, qoff, qx0, qy0, qz0, e20, qx1, qy1, qz1, e21);
    buildJ(JA, wrOfs, px, py, pz, e1, qx0, qy0, qz0, e20, qx1, qy1, qz1, e21);
    loadB(bS, Vf + ((unsigned)k0 >> 3) * 4096u, bOfs);
    loadQ(p2, k0 + 64, qoff, rx0, ry0, rz0, f20, rx1, ry1, rz1, f21);

    for (int jc = k0; jc < k0 + KS; jc += 128) {
        // ---- step A: consume JA+bS (k=jc); build JB; reload bS <- jc+64 ----
        LBAR();
        buildJ(JB, wrOfs, px, py, pz, e1, rx0, ry0, rz0, f20, rx1, ry1, rz1, f21);
        loadQ(p2, (jc + 128) & (N2 - 1), qoff, qx0, qy0, qz0, e20, qx1, qy1, qz1, e21);
        mfmaStep(acc, JA, bS, rdOfs);
        loadB(bS, Vf + ((unsigned)((jc + 64) & (N2 - 1)) >> 3) * 4096u, bOfs);
        // ---- step B: consume JB+bS (k=jc+64); build JA; reload bS <- jc+128 ----
        LBAR();
        buildJ(JA, wrOfs, px, py, pz, e1, qx0, qy0, qz0, e20, qx1, qy1, qz1, e21);
        loadQ(p2, (jc + 192) & (N2 - 1), qoff, rx0, ry0, rz0, f20, rx1, ry1, rz1, f21);
        mfmaStep(acc, JB, bS, rdOfs);
        loadB(bS, Vf + ((unsigned)((jc + 128) & (N2 - 1)) >> 3) * 4096u, bOfs);
    }

    // ---- store raw partial C as bf16, planar [comp][row][kc] ----
    unsigned short* outb = (ks ? pout1 : pout0) + (size_t)cg * PLANE;
    #pragma unroll
    for (int mr = 0; mr < 4; ++mr) {
        #pragma unroll
        for (int reg = 0; reg < 4; ++reg) {
            int row = i0 + mr * 16 + g * 4 + reg;
            #pragma unroll
            for (int nr = 0; nr < 2; ++nr) {
                int kc = w * 32 + nr * 16 + ln;
                outb[(size_t)row * 256 + kc] = bf16bits(acc[mr][nr][reg]);
            }
        }
    }
}

// Epilogue: block per row. Sum the two bf16 K-half partials, reduce row norm,
// scale to 16, rotate by conj(exp(i p1.A)), add exp(i p1.P), write f32 out.
__global__ __launch_bounds__(256) void epi_kernel(const float* __restrict__ p1,
                                                  const float* __restrict__ A,
                                                  const float* __restrict__ P,
                                                  const unsigned short* __restrict__ part0,
                                                  const unsigned short* __restrict__ part1,
                                                  float* __restrict__ out) {
    __shared__ float wsum[4];
    const int i = blockIdx.x;
    const int k = threadIdx.x;
    const size_t rofs = (size_t)i * 256 + k;
    const float gr = bf2f(part0[rofs]) + bf2f(part1[rofs]);
    const float gi = bf2f(part0[PLANE + rofs]) + bf2f(part1[PLANE + rofs]);

    float sq = fmaf(gr, gr, gi * gi);
    #pragma unroll
    for (int off = 1; off < 64; off <<= 1) sq += __shfl_xor(sq, off, 64);
    if ((k & 63) == 0) wsum[k >> 6] = sq;
    __syncthreads();
    const float ns = wsum[0] + wsum[1] + wsum[2] + wsum[3];
    const float scale = 16.0f * rsqrtf(ns);

    const float x = p1[(size_t)i * 3 + 0], y = p1[(size_t)i * 3 + 1], z = p1[(size_t)i * 3 + 2];
    float th1 = fmaf(x, A[k], fmaf(y, A[256 + k], z * A[512 + k]));
    float thp = fmaf(x, P[k], fmaf(y, P[256 + k], z * P[512 + k]));
    float s1, c1, sp, cp;
    fast_sincos(th1, s1, c1);
    fast_sincos(thp, sp, cp);
    float2 res;
    res.x = fmaf(gr, c1, gi * s1) * scale + cp;
    res.y = fmaf(gi, c1, -gr * s1) * scale + sp;
    *(float2*)(out + rofs * 2) = res;
}

extern "C" void kernel_launch(void* const* d_in, const int* in_sizes, int n_in,
                              void* d_out, int out_size, void* d_ws, size_t ws_size,
                              hipStream_t stream) {
    const float* p1 = (const float*)d_in[0];
    const float* p2 = (const float*)d_in[1];
    const float* A  = (const float*)d_in[2];
    const float* P  = (const float*)d_in[3];
    unsigned short* Vf = (unsigned short*)d_ws;                            // 8.39 MB
    unsigned short* part0 = (unsigned short*)((char*)d_ws + 8388608);      // 8.39 MB bf16 [2][8192][256]
    unsigned short* part1 = (unsigned short*)((char*)d_ws + 16777216);     // 8.39 MB bf16
    float* out = (float*)d_out;

    feat_kernel<<<N2 / 8, 512, 0, stream>>>(p2, A, Vf);
    gemm_kernel<<<512, 512, 0, stream>>>(p1, p2, Vf, part0, part1);
    epi_kernel<<<N1, 256, 0, stream>>>(p1, A, P, part0, part1, out);
}